// Round 12
// baseline (82.951 us; speedup 1.0000x reference)
//
#include <hip/hip_runtime.h>

#define IMG     512
#define VALID   506          // IMG - 6
#define NPLANES 96           // 32 * 3
#define R       17           // output rows per wave-band
#define NBANDS  30           // 30*17 = 510 >= 506 (no pad band needed)

struct Q { float4 x0, x1, y0, y1; };

__device__ __forceinline__ float shfl_next(float v, int baddr) {
    return __int_as_float(__builtin_amdgcn_ds_bpermute(baddr, __float_as_int(v)));
}
__device__ __forceinline__ void addv(float4& V, const float4 p) {
    V.x += p.x; V.y += p.y; V.z += p.z; V.w += p.w;
}
__device__ __forceinline__ void subv(float4& V, const float4 p) {
    V.x -= p.x; V.y -= p.y; V.z -= p.z; V.w -= p.w;
}
__device__ __forceinline__ void addmul(float4& V, const float4 p, const float4 q) {
    V.x = fmaf(p.x, q.x, V.x); V.y = fmaf(p.y, q.y, V.y);
    V.z = fmaf(p.z, q.z, V.z); V.w = fmaf(p.w, q.w, V.w);
}
__device__ __forceinline__ void submul(float4& V, const float4 p, const float4 q) {
    V.x = fmaf(-p.x, q.x, V.x); V.y = fmaf(-p.y, q.y, V.y);
    V.z = fmaf(-p.z, q.z, V.z); V.w = fmaf(-p.w, q.w, V.w);
}

// horizontal 7-tap sliding sums over this lane's 8 cols + 6 halo cols from lane+1
__device__ __forceinline__ void hsum7(const float4 A, const float4 B, int baddr, float o[8]) {
    float n0 = shfl_next(A.x, baddr);
    float n1 = shfl_next(A.y, baddr);
    float n2 = shfl_next(A.z, baddr);
    float n3 = shfl_next(A.w, baddr);
    float n4 = shfl_next(B.x, baddr);
    float n5 = shfl_next(B.y, baddr);
    o[0] = ((A.x + A.y) + (A.z + A.w)) + ((B.x + B.y) + B.z);
    o[1] = (o[0] - A.x) + B.w;
    o[2] = (o[1] - A.y) + n0;
    o[3] = (o[2] - A.z) + n1;
    o[4] = (o[3] - A.w) + n2;
    o[5] = (o[4] - B.x) + n3;
    o[6] = (o[5] - B.y) + n4;
    o[7] = (o[6] - B.z) + n5;
}

// async global->LDS, 16B per lane; LDS dest is wave-uniform base + lane*16
#define GLL(gp, lp) __builtin_amdgcn_global_load_lds(                          \
    (const __attribute__((address_space(1))) void*)(gp),                      \
    (__attribute__((address_space(3))) void*)(lp), 16, 0, 0)

#define VW(n) asm volatile("s_waitcnt vmcnt(" #n ")" ::: "memory")
#define LW()  asm volatile("s_waitcnt lgkmcnt(0)" ::: "memory")

// NOTE: plain __launch_bounds__(128). Any (N,minwaves) form pins VGPR=64 on
// this compiler (R5/R8: 257-333 MB scratch spill). Never add the 2nd arg.
__global__ __launch_bounds__(128) void ssim_gll_kernel(
    const float* __restrict__ pred,
    const float* __restrict__ target,
    double* __restrict__ accum)
{
    // per-wave private 3-slot ring: slot = 1024 floats (4KB):
    //   [0..255]   X even float4s (lane l @ 4l  = cols 8l..8l+3)
    //   [256..511] X odd  float4s (lane l      = cols 8l+4..8l+7)
    //   [512..767] Y even, [768..1023] Y odd
    __shared__ __align__(16) float lds[2 * 3 * 1024];   // 2 waves * 12KB = 24KB

    const int t     = threadIdx.x;
    const int lane  = t & 63;
    const int wv    = t >> 6;
    const int band  = blockIdx.y * 2 + wv;      // 0..29, all active
    const int plane = blockIdx.x;               // plane-major -> XCD locality
    const int row0  = band * R;
    const int col   = lane << 3;

    const size_t pbase = (size_t)plane * (IMG * IMG);
    const float* __restrict__ gx = pred   + pbase;
    const float* __restrict__ gy = target + pbase;
    float* wb = &lds[wv * 3072];

    const int baddr = ((lane + 1) & 63) << 2;

    float4 z = make_float4(0.f, 0.f, 0.f, 0.f);
    float4 Vx_a = z, Vx_b = z, Vy_a = z, Vy_b = z;
    float4 Vss_a = z, Vss_b = z, Vxy_a = z, Vxy_b = z;   // Vss = Vxx+Vyy merged

    float4 px0, px1, py0, py1;
    Q A, B;                                     // old-row ping-pong (VGPR)

#define STAGE(s, r) do { int _rr = (r); _rr = _rr < (IMG-1) ? _rr : (IMG-1);   \
    const float* _px = gx + (size_t)_rr * IMG + (lane << 3);                   \
    const float* _py = gy + (size_t)_rr * IMG + (lane << 3);                   \
    float* _lb = wb + (s) * 1024;                                              \
    GLL(_px,     _lb);                                                         \
    GLL(_px + 4, _lb + 256);                                                   \
    GLL(_py,     _lb + 512);                                                   \
    GLL(_py + 4, _lb + 768); } while (0)

#define READSLOT(s) do {                                                       \
    const float* _lr = wb + (s) * 1024 + (lane << 2);                          \
    px0 = *(const float4*)(_lr);        px1 = *(const float4*)(_lr + 256);     \
    py0 = *(const float4*)(_lr + 512);  py1 = *(const float4*)(_lr + 768); } while (0)

#define LOADQ(q, r) do {                                                       \
    const float4* _p  = reinterpret_cast<const float4*>(gx + (size_t)(r) * IMG + (lane << 3)); \
    const float4* _q2 = reinterpret_cast<const float4*>(gy + (size_t)(r) * IMG + (lane << 3)); \
    q.x0 = _p[0]; q.x1 = _p[1]; q.y0 = _q2[0]; q.y1 = _q2[1]; } while (0)

#define ACC4() do {                                                            \
    addv(Vx_a, px0); addv(Vx_b, px1); addv(Vy_a, py0); addv(Vy_b, py1);        \
    addmul(Vss_a, px0, px0); addmul(Vss_b, px1, px1);                          \
    addmul(Vss_a, py0, py0); addmul(Vss_b, py1, py1);                          \
    addmul(Vxy_a, px0, py0); addmul(Vxy_b, px1, py1); } while (0)

#define SUB4(q) do {                                                           \
    subv(Vx_a, q.x0); subv(Vx_b, q.x1); subv(Vy_a, q.y0); subv(Vy_b, q.y1);    \
    submul(Vss_a, q.x0, q.x0); submul(Vss_b, q.x1, q.x1);                      \
    submul(Vss_a, q.y0, q.y0); submul(Vss_b, q.y1, q.y1);                      \
    submul(Vxy_a, q.x0, q.y0); submul(Vxy_b, q.x1, q.y1); } while (0)

    const float c1 = 0.9604f;   // (0.01*2)^2 * 49^2
    const float c2 = 8.4672f;   // (0.03*2)^2 * 48*49
    float local = 0.f;

#define HSSIM(i) do { if ((row0 + (i)) < VALID) {                              \
    float hx[8], hy[8], hss[8], hxy[8];                                        \
    hsum7(Vx_a,  Vx_b,  baddr, hx);                                            \
    hsum7(Vy_a,  Vy_b,  baddr, hy);                                            \
    hsum7(Vss_a, Vss_b, baddr, hss);                                           \
    hsum7(Vxy_a, Vxy_b, baddr, hxy);                                           \
    _Pragma("unroll")                                                          \
    for (int j = 0; j < 8; ++j) {                                              \
        float t1 = hx[j] * hy[j];                                              \
        float t2 = fmaf(hx[j], hx[j], hy[j] * hy[j]);                          \
        float n1 = fmaf(2.f, t1, c1);                                          \
        float d1 = t2 + c1;                                                    \
        float n2 = fmaf(-2.f, t1, fmaf(98.f, hxy[j], c2));                     \
        float d2 = fmaf(49.f, hss[j], c2) - t2;                                \
        float S  = __fdividef(n1 * n2, d1 * d2);                               \
        local += (col + (j) < VALID) ? S : 0.f;                                \
    } } } while (0)

    // ---- prologue: stage r0..r2; stream r0..r5 through the ring ----
    STAGE(0, row0); STAGE(1, row0 + 1); STAGE(2, row0 + 2);
#define PSTEP(k, DOSTAGE) do {                                                 \
    VW(8);                   /* exact: 2 stage-groups newer than row k's */    \
    READSLOT((k) % 3);                                                         \
    ACC4();                                                                    \
    LW();                    /* reads of this slot complete before restage */  \
    if (DOSTAGE) STAGE((k) % 3, row0 + 3 + (k)); } while (0)
    PSTEP(0, 1); PSTEP(1, 1); PSTEP(2, 1);   // stage r3,r4,r5
    PSTEP(3, 1); PSTEP(4, 1);                // stage r6,r7
    PSTEP(5, 0);                             // r8+ staged by main loop
    LOADQ(A, row0);                          // old row for iter 1

    // ---- main: iter i reads r6+i (slot i%3), stages r8+i (slot (i+2)%3),
    //      loads old r_i into ping-pong, subtracts r_{i-1}. vmcnt(N) exact:
    //      N = vmem ops issued after the target stage-group. ----
#define STEP(i, RS, SS, NW, POLD, PNEW) do {                                   \
    VW(NW);                                                                    \
    READSLOT(RS);                                                              \
    if ((i) <= R - 3) STAGE(SS, row0 + 8 + (i));                               \
    if ((i) >= 1 && (i) <= R - 2) LOADQ(PNEW, row0 + (i));                     \
    ACC4();                                                                    \
    if ((i) >= 1) SUB4(POLD);                                                  \
    HSSIM(i); } while (0)

    STEP(0,  0, 2, 12, A, B);
    STEP(1,  1, 0, 12, A, B);
    STEP(2,  2, 1, 12, B, A);
    STEP(3,  0, 2, 20, A, B);
    STEP(4,  1, 0, 20, B, A);
    STEP(5,  2, 1, 20, A, B);
    STEP(6,  0, 2, 20, B, A);
    STEP(7,  1, 0, 20, A, B);
    STEP(8,  2, 1, 20, B, A);
    STEP(9,  0, 2, 20, A, B);
    STEP(10, 1, 0, 20, B, A);
    STEP(11, 2, 1, 20, A, B);
    STEP(12, 0, 2, 20, B, A);
    STEP(13, 1, 0, 20, A, B);
    STEP(14, 2, 1, 20, B, A);
    STEP(15, 0, 2, 20, A, B);
    STEP(16, 1, 0, 16, B, A);

    // per-wave reduce -> one atomic per wave, scattered per plane (no barriers)
    #pragma unroll
    for (int off = 32; off > 0; off >>= 1)
        local += __shfl_down(local, off, 64);
    if (lane == 0)
        atomicAdd(&accum[plane], (double)local);
}

__global__ void ssim_finalize_kernel(const double* __restrict__ accum,
                                     float* __restrict__ out)
{
    const int l = threadIdx.x;           // 64 threads = 1 wave
    double s = accum[l];
    if (l < NPLANES - 64) s += accum[64 + l];
    #pragma unroll
    for (int off = 32; off > 0; off >>= 1)
        s += __shfl_down(s, off, 64);
    if (l == 0) {
        const double n_valid = (double)NPLANES * (double)VALID * (double)VALID;
        out[0] = (float)(1.0 - s / n_valid);
    }
}

extern "C" void kernel_launch(void* const* d_in, const int* in_sizes, int n_in,
                              void* d_out, int out_size, void* d_ws, size_t ws_size,
                              hipStream_t stream) {
    const float* pred   = (const float*)d_in[0];
    const float* target = (const float*)d_in[1];
    float* out = (float*)d_out;
    double* accum = (double*)d_ws;

    hipMemsetAsync(d_ws, 0, NPLANES * sizeof(double), stream);

    // 96 x 15 grid of 128-thread (2-wave) blocks = 1440 blocks, 2880 waves.
    // LDS 24KB/block -> 6 blocks/CU -> 1536 slots: single generation (94%).
    dim3 grid(NPLANES, NBANDS / 2);
    ssim_gll_kernel<<<grid, 128, 0, stream>>>(pred, target, accum);
    ssim_finalize_kernel<<<1, 64, 0, stream>>>(accum, out);
}